// Round 7
// baseline (938.896 us; speedup 1.0000x reference)
//
#include <hip/hip_runtime.h>
#include <hip/hip_bf16.h>

// V=50000, D=512, H=512, L=4, E=40000
#define NV 50000
#define VP 50048           // 391*128, padded target count
#define ND 512
#define NH 512
#define NL 4
#define NE 40000
#define CAP 16             // per-(target,layer) list capacity; deg ~ Poisson(0.8)
#define KTOT 2048          // NL*ND concatenated K
#define NWG 782            // (VP/128) * (512/256) blocks for gemm_all
#define SWZ_Q 97           // NWG/8
#define SWZ_R 6            // NWG%8

typedef short bf16x8 __attribute__((ext_vector_type(8)));  // MFMA A/B frag
typedef float f32x4  __attribute__((ext_vector_type(4)));  // MFMA C/D frag

__device__ __forceinline__ unsigned short f2bf(float f) {
    unsigned int u = __float_as_uint(f);
    u += 0x7FFFu + ((u >> 16) & 1u);
    return (unsigned short)(u >> 16);
}
__device__ __forceinline__ unsigned pack_bf2(float x, float y) {
    return (unsigned)f2bf(x) | ((unsigned)f2bf(y) << 16);
}

// async global->LDS, 16B per lane; LDS dest is wave-uniform base + lane*16
#define GLL16(gp, lp) __builtin_amdgcn_global_load_lds( \
    (const __attribute__((address_space(1))) void*)(gp), \
    (__attribute__((address_space(3))) void*)(lp), 16, 0, 0)

// ---------------------------------------------------------------------------
// Wt2[h][l*512+k] = bf16(W[l][k][h])   (2 MiB at ws+0) — B^T, K-concat layout
// ---------------------------------------------------------------------------
__global__ void wt2_kernel(const float* __restrict__ W, unsigned short* __restrict__ Wt2) {
    int idx = blockIdx.x * 256 + threadIdx.x;     // NL*ND*NH = 4194304
    int l = idx >> 18;
    int r = idx & 262143;
    int k = r >> 9;
    int h = r & 511;
    Wt2[((size_t)h << 11) + (l << 9) + k] = f2bf(W[idx]);
}

// ---------------------------------------------------------------------------
// Per-(target,layer) edge lists: cell = tgt*NL + l, entry = src
// ---------------------------------------------------------------------------
__global__ void place_kernel(const int* __restrict__ adj, int* __restrict__ cnt,
                             int* __restrict__ list) {
    int i = blockIdx.x * 256 + threadIdx.x;       // NL*NE = 160000 exact
    int2 p = ((const int2*)adj)[i];               // p.x = src, p.y = tgt
    int l = i / NE;
    int cell = p.y * NL + l;
    int pos = atomicAdd(&cnt[cell], 1);
    if (pos < CAP) list[cell * CAP + pos] = p.x;
}

// ---------------------------------------------------------------------------
// Pass 1: one wave per (t,l). agg2[t][l*512 + d] (bf16 as u32 pairs)
//   = sum over in-edges of emb[src][d], f32 accumulate in regs.
// ---------------------------------------------------------------------------
__global__ void __launch_bounds__(256)
agg_pull(const float* __restrict__ emb, const int* __restrict__ cnt,
         const int* __restrict__ list, unsigned* __restrict__ agg2) {
    const int wid  = blockIdx.x * 4 + (threadIdx.x >> 6);   // over VP*NL
    const int lane = threadIdx.x & 63;
    const int t    = wid >> 2;
    const int l    = wid & 3;
    const int cell = wid;                                    // t*NL + l
    const size_t dst = (size_t)t * 1024 + l * 256 + lane;    // u32 units

    int n = cnt[cell]; if (n > CAP) n = CAP;
    const int* lst = list + cell * CAP;

    float2 s0 = {0.f,0.f}, s1 = {0.f,0.f}, s2 = {0.f,0.f}, s3 = {0.f,0.f};
    int j = 0;
    for (; j + 2 <= n; j += 2) {
        const float2* p0 = (const float2*)(emb + (size_t)lst[j]     * ND) + lane;
        const float2* p1 = (const float2*)(emb + (size_t)lst[j + 1] * ND) + lane;
        float2 a0 = p0[0], a1 = p0[64], a2 = p0[128], a3 = p0[192];
        float2 b0 = p1[0], b1 = p1[64], b2 = p1[128], b3 = p1[192];
        s0.x += a0.x + b0.x; s0.y += a0.y + b0.y;
        s1.x += a1.x + b1.x; s1.y += a1.y + b1.y;
        s2.x += a2.x + b2.x; s2.y += a2.y + b2.y;
        s3.x += a3.x + b3.x; s3.y += a3.y + b3.y;
    }
    if (j < n) {
        const float2* p0 = (const float2*)(emb + (size_t)lst[j] * ND) + lane;
        float2 a0 = p0[0], a1 = p0[64], a2 = p0[128], a3 = p0[192];
        s0.x += a0.x; s0.y += a0.y;  s1.x += a1.x; s1.y += a1.y;
        s2.x += a2.x; s2.y += a2.y;  s3.x += a3.x; s3.y += a3.y;
    }
    agg2[dst]       = pack_bf2(s0.x, s0.y);
    agg2[dst + 64]  = pack_bf2(s1.x, s1.y);
    agg2[dst + 128] = pack_bf2(s2.x, s2.y);
    agg2[dst + 192] = pack_bf2(s3.x, s3.y);
}

// ---------------------------------------------------------------------------
// Pass 2: out = relu(agg2[VP][2048] x Wt2[512][2048]^T).
// BM=128, BN=256, BK=64; LDS 48 KB -> 3 blocks/CU (24 waves/CU for TLP).
// 8 waves = 2M x 4N, per-wave 64x64 out, acc[4][4].
// global_load_lds staging (pre-swizzled source), swizzled ds_read, 2-barrier.
// Bijective XCD-chunk swizzle keeps the (nt=0,nt=1) pair of an M-tile on one
// XCD so the A-tile is HBM-fetched once and L2-reused.
// ---------------------------------------------------------------------------
__global__ void __launch_bounds__(512, 6)
gemm_all(const unsigned short* __restrict__ agg2,
         const unsigned short* __restrict__ Wt2,
         float* __restrict__ out) {
    __shared__ unsigned short s_a[128 * 64];   // 16 KiB
    __shared__ unsigned short s_b[256 * 64];   // 32 KiB

    // bijective chunked XCD swizzle (m204): logical-contiguous chunk per XCD
    const int orig = blockIdx.x;
    const int xcd = orig & 7, pos = orig >> 3;
    const int wgid = (xcd < SWZ_R ? xcd * (SWZ_Q + 1)
                                  : SWZ_R * (SWZ_Q + 1) + (xcd - SWZ_R) * SWZ_Q) + pos;
    const int mt = wgid >> 1, nt = wgid & 1;
    const int t0 = mt * 128, n0 = nt * 256;

    const int tid   = threadIdx.x;             // 0..511
    const int lane  = tid & 63;
    const int wave  = tid >> 6;                // 0..7
    const int wm    = wave >> 2;               // M half (0..1): 64 rows
    const int wn    = wave & 3;                // N quarter (0..3): 64 cols
    const int laneL = lane & 15, laneH = lane >> 4;

    // staging geometry: per round, wave covers LDS rows [r*64 + wave*8 + lane/8]
    const int srow  = wave * 8 + (lane >> 3);
    const int sslot = lane & 7;
    const unsigned short* aptr[2];
    const unsigned short* bptr[4];
#pragma unroll
    for (int r2 = 0; r2 < 2; ++r2) {
        int row = r2 * 64 + srow;
        aptr[r2] = agg2 + (size_t)(t0 + row) * KTOT + (sslot ^ (row & 7)) * 8;
    }
#pragma unroll
    for (int r4 = 0; r4 < 4; ++r4) {
        int row = r4 * 64 + srow;
        bptr[r4] = Wt2 + (size_t)(n0 + row) * KTOT + (sslot ^ (row & 7)) * 8;
    }
    unsigned short* alds = s_a + wave * 512;   // wave-uniform base (1 KiB/wave/round)
    unsigned short* blds = s_b + wave * 512;

    f32x4 acc[4][4];
#pragma unroll
    for (int mi = 0; mi < 4; ++mi)
#pragma unroll
        for (int ni = 0; ni < 4; ++ni)
            acc[mi][ni] = (f32x4){0.f, 0.f, 0.f, 0.f};

    for (int kt = 0; kt < KTOT / 64; ++kt) {
        const int ko = kt * 64;
        // ---- stage tile kt (async, linear LDS dest, pre-swizzled global src) ----
#pragma unroll
        for (int r2 = 0; r2 < 2; ++r2)
            GLL16(aptr[r2] + ko, alds + r2 * 4096);
#pragma unroll
        for (int r4 = 0; r4 < 4; ++r4)
            GLL16(bptr[r4] + ko, blds + r4 * 4096);
        __syncthreads();   // compiler drains vmcnt before barrier

        // ---- compute: 2 k-chunks of 32, 32 MFMA / wave ----
#pragma unroll
        for (int kk2 = 0; kk2 < 2; ++kk2) {
            const int slot = kk2 * 4 + laneH;
            bf16x8 a[4], b[4];
#pragma unroll
            for (int mi = 0; mi < 4; ++mi) {
                int row = wm * 64 + mi * 16 + laneL;
                a[mi] = *(const bf16x8*)(s_a + row * 64 + ((slot ^ (row & 7)) << 3));
            }
#pragma unroll
            for (int ni = 0; ni < 4; ++ni) {
                int row = wn * 64 + ni * 16 + laneL;
                b[ni] = *(const bf16x8*)(s_b + row * 64 + ((slot ^ (row & 7)) << 3));
            }
#pragma unroll
            for (int ni = 0; ni < 4; ++ni)
#pragma unroll
                for (int mi = 0; mi < 4; ++mi)
                    acc[mi][ni] = __builtin_amdgcn_mfma_f32_16x16x32_bf16(a[mi], b[ni], acc[mi][ni], 0, 0, 0);
        }
        __syncthreads();   // LDS reads done before next stage overwrites
    }

    // ---- epilogue: ReLU + direct stores (D: col=lane&15, row=(lane>>4)*4+i) ----
#pragma unroll
    for (int mi = 0; mi < 4; ++mi) {
#pragma unroll
        for (int i = 0; i < 4; ++i) {
            int row = wm * 64 + mi * 16 + laneH * 4 + i;
            int t = t0 + row;
            if (t < NV) {
#pragma unroll
                for (int ni = 0; ni < 4; ++ni) {
                    int h = n0 + wn * 64 + ni * 16 + laneL;
                    out[(size_t)t * NH + h] = fmaxf(acc[mi][ni][i], 0.f);
                }
            }
        }
    }
}

// ---------------------------------------------------------------------------
// Legacy fallback (R1 pipeline) if workspace is too small for agg2.
// ---------------------------------------------------------------------------
__global__ void wt_legacy(const float* __restrict__ W, unsigned short* __restrict__ Wt) {
    int idx = blockIdx.x * 256 + threadIdx.x;
    int l = idx >> 18;
    int r = idx & 262143;
    int k = r >> 9;
    int h = r & 511;
    Wt[(l << 18) + (h << 9) + k] = f2bf(W[idx]);
}
__global__ void __launch_bounds__(256)
legacy_msg(const float* __restrict__ emb, const int* __restrict__ adj,
           const unsigned short* __restrict__ Wt, float* __restrict__ out) {
    __shared__ bf16x8 s_a[32 * 64];
    __shared__ int s_src[32];
    __shared__ int s_tgt[32];
    const int bx = blockIdx.x;
    const int l = bx / (NE / 32);
    const int ebase = (bx % (NE / 32)) * 32;
    const int tid = threadIdx.x, lane = tid & 63, wave = tid >> 6;
    if (tid < 32) {
        int2 p = *(const int2*)(adj + ((size_t)l * NE + ebase + tid) * 2);
        s_src[tid] = p.x; s_tgt[tid] = p.y;
    }
    __syncthreads();
    {
        const int r = tid >> 3, part = tid & 7, k0 = part * 64, rxx = r & 7;
        const float* g = emb + (size_t)s_src[r] * ND + k0;
#pragma unroll
        for (int j = 0; j < 8; ++j) {
            float4 f0 = *(const float4*)(g + j * 8);
            float4 f1 = *(const float4*)(g + j * 8 + 4);
            bf16x8 v;
            v[0]=(short)f2bf(f0.x); v[1]=(short)f2bf(f0.y);
            v[2]=(short)f2bf(f0.z); v[3]=(short)f2bf(f0.w);
            v[4]=(short)f2bf(f1.x); v[5]=(short)f2bf(f1.y);
            v[6]=(short)f2bf(f1.z); v[7]=(short)f2bf(f1.w);
            int slot = (k0 >> 3) + j;
            s_a[r * 64 + (slot ^ rxx)] = v;
        }
    }
    __syncthreads();
    const int c0 = wave * 128, laneL = lane & 15, laneH = lane >> 4, arx = laneL & 7;
    f32x4 acc[2][8];
#pragma unroll
    for (int mf = 0; mf < 2; ++mf)
#pragma unroll
        for (int nf = 0; nf < 8; ++nf) acc[mf][nf] = (f32x4){0.f,0.f,0.f,0.f};
    const bf16x8* wb = (const bf16x8*)(Wt + ((size_t)l << 18));
#pragma unroll
    for (int kc = 0; kc < 16; ++kc) {
        int slot = kc * 4 + laneH;
        bf16x8 a0 = s_a[laneL * 64 + (slot ^ arx)];
        bf16x8 a1 = s_a[(16 + laneL) * 64 + (slot ^ arx)];
#pragma unroll
        for (int nf = 0; nf < 8; ++nf) {
            bf16x8 b = wb[(c0 + nf * 16 + laneL) * 64 + slot];
            acc[0][nf] = __builtin_amdgcn_mfma_f32_16x16x32_bf16(a0, b, acc[0][nf], 0, 0, 0);
            acc[1][nf] = __builtin_amdgcn_mfma_f32_16x16x32_bf16(a1, b, acc[1][nf], 0, 0, 0);
        }
    }
#pragma unroll
    for (int mf = 0; mf < 2; ++mf)
#pragma unroll
        for (int nf = 0; nf < 8; ++nf) {
            int h = c0 + nf * 16 + laneL;
#pragma unroll
            for (int i = 0; i < 4; ++i) {
                int er = mf * 16 + laneH * 4 + i;
                atomicAdd(out + (size_t)s_tgt[er] * NH + h, acc[mf][nf][i]);
            }
        }
}
__global__ void legacy_relu(float* __restrict__ o, int n4) {
    int stride = gridDim.x * blockDim.x;
    for (int i = blockIdx.x * blockDim.x + threadIdx.x; i < n4; i += stride) {
        float4 v = ((float4*)o)[i];
        v.x = fmaxf(v.x, 0.f); v.y = fmaxf(v.y, 0.f);
        v.z = fmaxf(v.z, 0.f); v.w = fmaxf(v.w, 0.f);
        ((float4*)o)[i] = v;
    }
}

extern "C" void kernel_launch(void* const* d_in, const int* in_sizes, int n_in,
                              void* d_out, int out_size, void* d_ws, size_t ws_size,
                              hipStream_t stream) {
    const float* emb = (const float*)d_in[0];   // [V, D] f32
    const int*   adj = (const int*)d_in[1];     // [L, E, 2] i32
    const float* W   = (const float*)d_in[2];   // [L, D, H] f32
    float* out = (float*)d_out;                 // [V, H] f32
    char* ws = (char*)d_ws;

    unsigned short* Wt2  = (unsigned short*)ws;                 // @0,   2 MiB (4 reserved)
    int*            cnt  = (int*)(ws + (4u << 20));             // @4M,  800,768 B
    int*            list = (int*)(ws + (5u << 20));             // @5M,  12.8 MB
    unsigned short* agg2 = (unsigned short*)(ws + (19u << 20)); // @19M, 205 MB

    const size_t need = (19u << 20) + (size_t)VP * KTOT * 2;    // ~224 MB

    if (ws_size >= need) {
        hipMemsetAsync(cnt, 0, (size_t)VP * NL * sizeof(int), stream);
        wt2_kernel<<<(NL * ND * NH) / 256, 256, 0, stream>>>(W, Wt2);
        place_kernel<<<(NL * NE) / 256, 256, 0, stream>>>(adj, cnt, list);
        agg_pull<<<(VP * NL) / 4, 256, 0, stream>>>(emb, cnt, list, (unsigned*)agg2);
        gemm_all<<<NWG, 512, 0, stream>>>(agg2, Wt2, out);
    } else {
        // legacy scatter path (R1)
        hipMemsetAsync(d_out, 0, (size_t)out_size * sizeof(float), stream);
        wt_legacy<<<(NL * ND * NH) / 256, 256, 0, stream>>>(W, Wt2);
        legacy_msg<<<NL * (NE / 32), 256, 0, stream>>>(emb, adj, Wt2, out);
        legacy_relu<<<2048, 256, 0, stream>>>(out, out_size / 4);
    }
}

// Round 8
// 285.888 us; speedup vs baseline: 3.2841x; 3.2841x over previous
//
#include <hip/hip_runtime.h>
#include <hip/hip_bf16.h>

// V=50000, D=512, H=512, L=4, E=40000
#define NV 50000
#define VP 50048           // 391*128, padded target count
#define ND 512
#define NH 512
#define NL 4
#define NE 40000
#define CAP 16             // per-(target,layer) list capacity; deg ~ Poisson(0.8)
#define KTOT 2048          // NL*ND concatenated K
#define NWG 1564           // (VP/128) * (512/128) blocks for gemm_all
#define SWZ_Q 195          // NWG/8
#define SWZ_R 4            // NWG%8

typedef short bf16x8 __attribute__((ext_vector_type(8)));  // MFMA A/B frag
typedef float f32x4  __attribute__((ext_vector_type(4)));  // MFMA C/D frag

__device__ __forceinline__ unsigned short f2bf(float f) {
    unsigned int u = __float_as_uint(f);
    u += 0x7FFFu + ((u >> 16) & 1u);
    return (unsigned short)(u >> 16);
}
__device__ __forceinline__ unsigned pack_bf2(float x, float y) {
    return (unsigned)f2bf(x) | ((unsigned)f2bf(y) << 16);
}

// async global->LDS, 16B per lane; LDS dest is wave-uniform base + lane*16
#define GLL16(gp, lp) __builtin_amdgcn_global_load_lds( \
    (const __attribute__((address_space(1))) void*)(gp), \
    (__attribute__((address_space(3))) void*)(lp), 16, 0, 0)

// ---------------------------------------------------------------------------
// Wt2[h][l*512+k] = bf16(W[l][k][h])   (2 MiB at ws+0) — B^T, K-concat layout
// ---------------------------------------------------------------------------
__global__ void wt2_kernel(const float* __restrict__ W, unsigned short* __restrict__ Wt2) {
    int idx = blockIdx.x * 256 + threadIdx.x;     // NL*ND*NH = 4194304
    int l = idx >> 18;
    int r = idx & 262143;
    int k = r >> 9;
    int h = r & 511;
    Wt2[((size_t)h << 11) + (l << 9) + k] = f2bf(W[idx]);
}

// ---------------------------------------------------------------------------
// Per-(target,layer) edge lists: cell = tgt*NL + l, entry = src
// ---------------------------------------------------------------------------
__global__ void place_kernel(const int* __restrict__ adj, int* __restrict__ cnt,
                             int* __restrict__ list) {
    int i = blockIdx.x * 256 + threadIdx.x;       // NL*NE = 160000 exact
    int2 p = ((const int2*)adj)[i];               // p.x = src, p.y = tgt
    int l = i / NE;
    int cell = p.y * NL + l;
    int pos = atomicAdd(&cnt[cell], 1);
    if (pos < CAP) list[cell * CAP + pos] = p.x;
}

// ---------------------------------------------------------------------------
// Pass 1: one wave per (t,l). agg2[t][l*512 + d] (bf16 as u32 pairs)
//   = sum over in-edges of emb[src][d], f32 accumulate in regs.
// ---------------------------------------------------------------------------
__global__ void __launch_bounds__(256)
agg_pull(const float* __restrict__ emb, const int* __restrict__ cnt,
         const int* __restrict__ list, unsigned* __restrict__ agg2) {
    const int wid  = blockIdx.x * 4 + (threadIdx.x >> 6);   // over VP*NL
    const int lane = threadIdx.x & 63;
    const int t    = wid >> 2;
    const int l    = wid & 3;
    const int cell = wid;                                    // t*NL + l
    const size_t dst = (size_t)t * 1024 + l * 256 + lane;    // u32 units

    int n = cnt[cell]; if (n > CAP) n = CAP;
    const int* lst = list + cell * CAP;

    float2 s0 = {0.f,0.f}, s1 = {0.f,0.f}, s2 = {0.f,0.f}, s3 = {0.f,0.f};
    int j = 0;
    for (; j + 2 <= n; j += 2) {
        const float2* p0 = (const float2*)(emb + (size_t)lst[j]     * ND) + lane;
        const float2* p1 = (const float2*)(emb + (size_t)lst[j + 1] * ND) + lane;
        float2 a0 = p0[0], a1 = p0[64], a2 = p0[128], a3 = p0[192];
        float2 b0 = p1[0], b1 = p1[64], b2 = p1[128], b3 = p1[192];
        s0.x += a0.x + b0.x; s0.y += a0.y + b0.y;
        s1.x += a1.x + b1.x; s1.y += a1.y + b1.y;
        s2.x += a2.x + b2.x; s2.y += a2.y + b2.y;
        s3.x += a3.x + b3.x; s3.y += a3.y + b3.y;
    }
    if (j < n) {
        const float2* p0 = (const float2*)(emb + (size_t)lst[j] * ND) + lane;
        float2 a0 = p0[0], a1 = p0[64], a2 = p0[128], a3 = p0[192];
        s0.x += a0.x; s0.y += a0.y;  s1.x += a1.x; s1.y += a1.y;
        s2.x += a2.x; s2.y += a2.y;  s3.x += a3.x; s3.y += a3.y;
    }
    agg2[dst]       = pack_bf2(s0.x, s0.y);
    agg2[dst + 64]  = pack_bf2(s1.x, s1.y);
    agg2[dst + 128] = pack_bf2(s2.x, s2.y);
    agg2[dst + 192] = pack_bf2(s3.x, s3.y);
}

// ---------------------------------------------------------------------------
// Pass 2: out = relu(agg2[VP][2048] x Wt2[512][2048]^T).
// m97-proven config: BM=BN=128, BK=64, 256 threads (4 waves, 2x2, 64x64/wave,
// acc[4][4]), LDS 32 KB, NO restrictive launch bounds (VGPR free -> 3-4
// blocks/CU). global_load_lds staging (pre-swizzled src), swizzled ds_read,
// 2-barrier K-loop. Bijective chunked XCD swizzle: 4 N-tiles of an M-tile on
// one XCD -> A HBM-fetched once; B (2 MB) L2-resident.
// ---------------------------------------------------------------------------
__global__ void __launch_bounds__(256)
gemm_all(const unsigned short* __restrict__ agg2,
         const unsigned short* __restrict__ Wt2,
         float* __restrict__ out) {
    __shared__ unsigned short s_a[128 * 64];   // 16 KiB, [row][slot^(row&7)] 16B slots
    __shared__ unsigned short s_b[128 * 64];   // 16 KiB

    // bijective chunked XCD swizzle (m204)
    const int orig = blockIdx.x;
    const int xcd = orig & 7, pos = orig >> 3;
    const int wgid = (xcd < SWZ_R ? xcd * (SWZ_Q + 1)
                                  : SWZ_R * (SWZ_Q + 1) + (xcd - SWZ_R) * SWZ_Q) + pos;
    const int mt = wgid >> 2, nt = wgid & 3;
    const int t0 = mt * 128, n0 = nt * 128;

    const int tid   = threadIdx.x;             // 0..255
    const int lane  = tid & 63;
    const int wave  = tid >> 6;                // 0..3
    const int wm    = wave >> 1;               // M half (0..1): 64 rows
    const int wn    = wave & 1;                // N half (0..1): 64 cols
    const int laneL = lane & 15, laneH = lane >> 4;

    // staging geometry: per round, block covers 32 rows (8 slots each);
    // wave w covers rows [r*32 + w*8 + lane/8], slot lane&7 (pre-swizzled src)
    const int srow  = wave * 8 + (lane >> 3);
    const int sslot = lane & 7;
    const unsigned short* aptr[4];
    const unsigned short* bptr[4];
#pragma unroll
    for (int r4 = 0; r4 < 4; ++r4) {
        int row = r4 * 32 + srow;
        aptr[r4] = agg2 + (size_t)(t0 + row) * KTOT + (sslot ^ (row & 7)) * 8;
        bptr[r4] = Wt2  + (size_t)(n0 + row) * KTOT + (sslot ^ (row & 7)) * 8;
    }
    unsigned short* alds = s_a + wave * 512;   // wave-uniform base (1 KiB/wave/round)
    unsigned short* blds = s_b + wave * 512;

    f32x4 acc[4][4];
#pragma unroll
    for (int mi = 0; mi < 4; ++mi)
#pragma unroll
        for (int ni = 0; ni < 4; ++ni)
            acc[mi][ni] = (f32x4){0.f, 0.f, 0.f, 0.f};

    for (int kt = 0; kt < KTOT / 64; ++kt) {
        const int ko = kt * 64;
        // ---- stage tile kt (async, linear LDS dest, pre-swizzled global src) ----
#pragma unroll
        for (int r4 = 0; r4 < 4; ++r4) {
            GLL16(aptr[r4] + ko, alds + r4 * 2048);
            GLL16(bptr[r4] + ko, blds + r4 * 2048);
        }
        __syncthreads();   // compiler drains vmcnt before barrier

        // ---- compute: 2 k-chunks of 32, 32 MFMA / wave ----
#pragma unroll
        for (int kk2 = 0; kk2 < 2; ++kk2) {
            const int slot = kk2 * 4 + laneH;
            bf16x8 a[4], b[4];
#pragma unroll
            for (int mi = 0; mi < 4; ++mi) {
                int row = wm * 64 + mi * 16 + laneL;
                a[mi] = *(const bf16x8*)(s_a + row * 64 + ((slot ^ (row & 7)) << 3));
            }
#pragma unroll
            for (int ni = 0; ni < 4; ++ni) {
                int row = wn * 64 + ni * 16 + laneL;
                b[ni] = *(const bf16x8*)(s_b + row * 64 + ((slot ^ (row & 7)) << 3));
            }
#pragma unroll
            for (int ni = 0; ni < 4; ++ni)
#pragma unroll
                for (int mi = 0; mi < 4; ++mi)
                    acc[mi][ni] = __builtin_amdgcn_mfma_f32_16x16x32_bf16(a[mi], b[ni], acc[mi][ni], 0, 0, 0);
        }
        __syncthreads();   // LDS reads done before next stage overwrites
    }

    // ---- epilogue: ReLU + direct stores (D: col=lane&15, row=(lane>>4)*4+i) ----
#pragma unroll
    for (int mi = 0; mi < 4; ++mi) {
#pragma unroll
        for (int i = 0; i < 4; ++i) {
            int row = wm * 64 + mi * 16 + laneH * 4 + i;
            int t = t0 + row;
            if (t < NV) {
#pragma unroll
                for (int ni = 0; ni < 4; ++ni) {
                    int h = n0 + wn * 64 + ni * 16 + laneL;
                    out[(size_t)t * NH + h] = fmaxf(acc[mi][ni][i], 0.f);
                }
            }
        }
    }
}

// ---------------------------------------------------------------------------
// Legacy fallback (R1 pipeline) if workspace is too small for agg2.
// ---------------------------------------------------------------------------
__global__ void wt_legacy(const float* __restrict__ W, unsigned short* __restrict__ Wt) {
    int idx = blockIdx.x * 256 + threadIdx.x;
    int l = idx >> 18;
    int r = idx & 262143;
    int k = r >> 9;
    int h = r & 511;
    Wt[(l << 18) + (h << 9) + k] = f2bf(W[idx]);
}
__global__ void __launch_bounds__(256)
legacy_msg(const float* __restrict__ emb, const int* __restrict__ adj,
           const unsigned short* __restrict__ Wt, float* __restrict__ out) {
    __shared__ bf16x8 s_a[32 * 64];
    __shared__ int s_src[32];
    __shared__ int s_tgt[32];
    const int bx = blockIdx.x;
    const int l = bx / (NE / 32);
    const int ebase = (bx % (NE / 32)) * 32;
    const int tid = threadIdx.x, lane = tid & 63, wave = tid >> 6;
    if (tid < 32) {
        int2 p = *(const int2*)(adj + ((size_t)l * NE + ebase + tid) * 2);
        s_src[tid] = p.x; s_tgt[tid] = p.y;
    }
    __syncthreads();
    {
        const int r = tid >> 3, part = tid & 7, k0 = part * 64, rxx = r & 7;
        const float* g = emb + (size_t)s_src[r] * ND + k0;
#pragma unroll
        for (int j = 0; j < 8; ++j) {
            float4 f0 = *(const float4*)(g + j * 8);
            float4 f1 = *(const float4*)(g + j * 8 + 4);
            bf16x8 v;
            v[0]=(short)f2bf(f0.x); v[1]=(short)f2bf(f0.y);
            v[2]=(short)f2bf(f0.z); v[3]=(short)f2bf(f0.w);
            v[4]=(short)f2bf(f1.x); v[5]=(short)f2bf(f1.y);
            v[6]=(short)f2bf(f1.z); v[7]=(short)f2bf(f1.w);
            int slot = (k0 >> 3) + j;
            s_a[r * 64 + (slot ^ rxx)] = v;
        }
    }
    __syncthreads();
    const int c0 = wave * 128, laneL = lane & 15, laneH = lane >> 4, arx = laneL & 7;
    f32x4 acc[2][8];
#pragma unroll
    for (int mf = 0; mf < 2; ++mf)
#pragma unroll
        for (int nf = 0; nf < 8; ++nf) acc[mf][nf] = (f32x4){0.f,0.f,0.f,0.f};
    const bf16x8* wb = (const bf16x8*)(Wt + ((size_t)l << 18));
#pragma unroll
    for (int kc = 0; kc < 16; ++kc) {
        int slot = kc * 4 + laneH;
        bf16x8 a0 = s_a[laneL * 64 + (slot ^ arx)];
        bf16x8 a1 = s_a[(16 + laneL) * 64 + (slot ^ arx)];
#pragma unroll
        for (int nf = 0; nf < 8; ++nf) {
            bf16x8 b = wb[(c0 + nf * 16 + laneL) * 64 + slot];
            acc[0][nf] = __builtin_amdgcn_mfma_f32_16x16x32_bf16(a0, b, acc[0][nf], 0, 0, 0);
            acc[1][nf] = __builtin_amdgcn_mfma_f32_16x16x32_bf16(a1, b, acc[1][nf], 0, 0, 0);
        }
    }
#pragma unroll
    for (int mf = 0; mf < 2; ++mf)
#pragma unroll
        for (int nf = 0; nf < 8; ++nf) {
            int h = c0 + nf * 16 + laneL;
#pragma unroll
            for (int i = 0; i < 4; ++i) {
                int er = mf * 16 + laneH * 4 + i;
                atomicAdd(out + (size_t)s_tgt[er] * NH + h, acc[mf][nf][i]);
            }
        }
}
__global__ void legacy_relu(float* __restrict__ o, int n4) {
    int stride = gridDim.x * blockDim.x;
    for (int i = blockIdx.x * blockDim.x + threadIdx.x; i < n4; i += stride) {
        float4 v = ((float4*)o)[i];
        v.x = fmaxf(v.x, 0.f); v.y = fmaxf(v.y, 0.f);
        v.z = fmaxf(v.z, 0.f); v.w = fmaxf(v.w, 0.f);
        ((float4*)o)[i] = v;
    }
}

extern "C" void kernel_launch(void* const* d_in, const int* in_sizes, int n_in,
                              void* d_out, int out_size, void* d_ws, size_t ws_size,
                              hipStream_t stream) {
    const float* emb = (const float*)d_in[0];   // [V, D] f32
    const int*   adj = (const int*)d_in[1];     // [L, E, 2] i32
    const float* W   = (const float*)d_in[2];   // [L, D, H] f32
    float* out = (float*)d_out;                 // [V, H] f32
    char* ws = (char*)d_ws;

    unsigned short* Wt2  = (unsigned short*)ws;                 // @0,   2 MiB (4 reserved)
    int*            cnt  = (int*)(ws + (4u << 20));             // @4M,  800,768 B
    int*            list = (int*)(ws + (5u << 20));             // @5M,  12.8 MB
    unsigned short* agg2 = (unsigned short*)(ws + (19u << 20)); // @19M, 205 MB

    const size_t need = (19u << 20) + (size_t)VP * KTOT * 2;    // ~224 MB

    if (ws_size >= need) {
        hipMemsetAsync(cnt, 0, (size_t)VP * NL * sizeof(int), stream);
        wt2_kernel<<<(NL * ND * NH) / 256, 256, 0, stream>>>(W, Wt2);
        place_kernel<<<(NL * NE) / 256, 256, 0, stream>>>(adj, cnt, list);
        agg_pull<<<(VP * NL) / 4, 256, 0, stream>>>(emb, cnt, list, (unsigned*)agg2);
        gemm_all<<<NWG, 256, 0, stream>>>(agg2, Wt2, out);
    } else {
        // legacy scatter path (R1)
        hipMemsetAsync(d_out, 0, (size_t)out_size * sizeof(float), stream);
        wt_legacy<<<(NL * ND * NH) / 256, 256, 0, stream>>>(W, Wt2);
        legacy_msg<<<NL * (NE / 32), 256, 0, stream>>>(emb, adj, Wt2, out);
        legacy_relu<<<2048, 256, 0, stream>>>(out, out_size / 4);
    }
}

// Round 9
// 272.029 us; speedup vs baseline: 3.4515x; 1.0509x over previous
//
#include <hip/hip_runtime.h>
#include <hip/hip_bf16.h>

// V=50000, D=512, H=512, L=4, E=40000
#define NV 50000
#define VP2 50176          // 196*256, padded target count (M of the big GEMM)
#define ND 512
#define NH 512
#define NL 4
#define NE 40000
#define CAP 16             // per-(target,layer) list capacity; deg ~ Poisson(0.8)
#define KTOT 2048          // NL*ND concatenated K
#define NKT 32             // K-tiles of 64
#define NWG2 392           // (VP2/256) * (512/256) blocks; 392 = 8*49

typedef short bf16x8 __attribute__((ext_vector_type(8)));  // MFMA A/B frag
typedef float f32x4  __attribute__((ext_vector_type(4)));  // MFMA C/D frag

__device__ __forceinline__ unsigned short f2bf(float f) {
    unsigned int u = __float_as_uint(f);
    u += 0x7FFFu + ((u >> 16) & 1u);
    return (unsigned short)(u >> 16);
}
__device__ __forceinline__ unsigned pack_bf2(float x, float y) {
    return (unsigned)f2bf(x) | ((unsigned)f2bf(y) << 16);
}

// async global->LDS, 16B per lane; LDS dest is wave-uniform base + lane*16
#define GLL16(gp, lp) __builtin_amdgcn_global_load_lds( \
    (const __attribute__((address_space(1))) void*)(gp), \
    (__attribute__((address_space(3))) void*)(lp), 16, 0, 0)

#define SBAR   __builtin_amdgcn_s_barrier()
#define SCHED0 __builtin_amdgcn_sched_barrier(0)
#define PRIO1  __builtin_amdgcn_s_setprio(1)
#define PRIO0  __builtin_amdgcn_s_setprio(0)
#define VMCNT0 asm volatile("s_waitcnt vmcnt(0)" ::: "memory")
#define LGKM0  asm volatile("s_waitcnt lgkmcnt(0)" ::: "memory")

// ---------------------------------------------------------------------------
// Wt2[h][l*512+k] = bf16(W[l][k][h])   (2 MiB at ws+0) — B^T, K-concat layout
// ---------------------------------------------------------------------------
__global__ void wt2_kernel(const float* __restrict__ W, unsigned short* __restrict__ Wt2) {
    int idx = blockIdx.x * 256 + threadIdx.x;     // NL*ND*NH = 4194304
    int l = idx >> 18;
    int r = idx & 262143;
    int k = r >> 9;
    int h = r & 511;
    Wt2[((size_t)h << 11) + (l << 9) + k] = f2bf(W[idx]);
}

// ---------------------------------------------------------------------------
// Per-(target,layer) edge lists: cell = tgt*NL + l, entry = src
// ---------------------------------------------------------------------------
__global__ void place_kernel(const int* __restrict__ adj, int* __restrict__ cnt,
                             int* __restrict__ list) {
    int i = blockIdx.x * 256 + threadIdx.x;       // NL*NE = 160000 exact
    int2 p = ((const int2*)adj)[i];               // p.x = src, p.y = tgt
    int l = i / NE;
    int cell = p.y * NL + l;
    int pos = atomicAdd(&cnt[cell], 1);
    if (pos < CAP) list[cell * CAP + pos] = p.x;
}

// ---------------------------------------------------------------------------
// Pass 1: one wave per (t,l). agg2[t][l*512 + d] (bf16 as u32 pairs)
//   = sum over in-edges of emb[src][d], f32 accumulate in regs.
// ---------------------------------------------------------------------------
__global__ void __launch_bounds__(256)
agg_pull(const float* __restrict__ emb, const int* __restrict__ cnt,
         const int* __restrict__ list, unsigned* __restrict__ agg2) {
    const int wid  = blockIdx.x * 4 + (threadIdx.x >> 6);   // over VP2*NL
    const int lane = threadIdx.x & 63;
    const int t    = wid >> 2;
    const int l    = wid & 3;
    const int cell = wid;                                    // t*NL + l
    const size_t dst = (size_t)t * 1024 + l * 256 + lane;    // u32 units

    int n = cnt[cell]; if (n > CAP) n = CAP;
    const int* lst = list + cell * CAP;

    float2 s0 = {0.f,0.f}, s1 = {0.f,0.f}, s2 = {0.f,0.f}, s3 = {0.f,0.f};
    int j = 0;
    for (; j + 2 <= n; j += 2) {
        const float2* p0 = (const float2*)(emb + (size_t)lst[j]     * ND) + lane;
        const float2* p1 = (const float2*)(emb + (size_t)lst[j + 1] * ND) + lane;
        float2 a0 = p0[0], a1 = p0[64], a2 = p0[128], a3 = p0[192];
        float2 b0 = p1[0], b1 = p1[64], b2 = p1[128], b3 = p1[192];
        s0.x += a0.x + b0.x; s0.y += a0.y + b0.y;
        s1.x += a1.x + b1.x; s1.y += a1.y + b1.y;
        s2.x += a2.x + b2.x; s2.y += a2.y + b2.y;
        s3.x += a3.x + b3.x; s3.y += a3.y + b3.y;
    }
    if (j < n) {
        const float2* p0 = (const float2*)(emb + (size_t)lst[j] * ND) + lane;
        float2 a0 = p0[0], a1 = p0[64], a2 = p0[128], a3 = p0[192];
        s0.x += a0.x; s0.y += a0.y;  s1.x += a1.x; s1.y += a1.y;
        s2.x += a2.x; s2.y += a2.y;  s3.x += a3.x; s3.y += a3.y;
    }
    agg2[dst]       = pack_bf2(s0.x, s0.y);
    agg2[dst + 64]  = pack_bf2(s1.x, s1.y);
    agg2[dst + 128] = pack_bf2(s2.x, s2.y);
    agg2[dst + 192] = pack_bf2(s3.x, s3.y);
}

// ---------------------------------------------------------------------------
// Stage one half-tile s (= tile*4 + part; part 0=A-lo,1=A-hi,2=B-lo,3=B-hi).
// Linear LDS dest (wave-uniform base), pre-swizzled global source slot so the
// LDS content at (row, slot) holds global slot (slot ^ (row&7)).
// ---------------------------------------------------------------------------
__device__ __forceinline__ void stage_ht(
    int s, int t0, int n0, int wave, int lane,
    const unsigned short* __restrict__ agg2, const unsigned short* __restrict__ Wt2,
    unsigned short* sa0, unsigned short* sa1,
    unsigned short* sb0, unsigned short* sb1) {
    const int tile  = s >> 2, part = s & 3;
    const int lr8   = (part & 1) << 7;           // row base within 256-row tile
    const int rowin = lane >> 3;                 // 0..7
    const int slt   = (lane & 7) ^ rowin;        // pre-swizzled 16B slot
    const bool isA  = part < 2;
    const unsigned short* gsrc = isA ? agg2 : Wt2;
    const int gr0 = isA ? t0 : n0;
    unsigned short* ldsbase = isA ? ((tile & 1) ? sa1 : sa0)
                                  : ((tile & 1) ? sb1 : sb0);
#pragma unroll
    for (int c = 0; c < 2; ++c) {
        const int lr = lr8 + (wave * 2 + c) * 8;                     // wave-uniform
        const unsigned short* src = gsrc
            + (size_t)(gr0 + lr + rowin) * KTOT + tile * 64 + slt * 8;
        GLL16(src, ldsbase + lr * 64);
    }
}

// ---------------------------------------------------------------------------
// One K-tile = 4 phases. Each phase: [ds_read frag subtile | stage next-tile
// half-tiles] -> s_barrier -> lgkmcnt(0) -> setprio(1) -> 16 MFMA ->
// setprio(0) -> s_barrier. vmcnt(0) once per tile at P4 (stages were issued
// 2-4 phases earlier -> latency mostly hidden).
// ---------------------------------------------------------------------------
template<bool STG, bool VMW>
__device__ __forceinline__ void group4(
    int kt, int t0, int n0, int wave, int lane, int wm, int wn,
    const unsigned short* __restrict__ agg2, const unsigned short* __restrict__ Wt2,
    unsigned short* sa0, unsigned short* sa1,
    unsigned short* sb0, unsigned short* sb1,
    f32x4 (&acc)[8][4]) {
    const int laneL = lane & 15, laneH = lane >> 4;
    const int ax = laneL & 7;
    const unsigned short* pa = (kt & 1) ? sa1 : sa0;
    const unsigned short* pb = (kt & 1) ? sb1 : sb0;
    const int s1 = (kt + 1) * 4;
    bf16x8 aF[4][2], bF[4][2];

    // ---- P1: read a(mi 0..3) + b(ni 0..1); stage A-lo,A-hi of tile kt+1 ----
#pragma unroll
    for (int mi = 0; mi < 4; ++mi)
#pragma unroll
        for (int ks = 0; ks < 2; ++ks) {
            const int row = wm * 128 + mi * 16 + laneL;
            aF[mi][ks] = *(const bf16x8*)(pa + row * 64 + (((ks * 4 + laneH) ^ ax) << 3));
        }
#pragma unroll
    for (int ni = 0; ni < 2; ++ni)
#pragma unroll
        for (int ks = 0; ks < 2; ++ks) {
            const int row = wn * 64 + ni * 16 + laneL;
            bF[ni][ks] = *(const bf16x8*)(pb + row * 64 + (((ks * 4 + laneH) ^ ax) << 3));
        }
    if (STG) {
        stage_ht(s1 + 0, t0, n0, wave, lane, agg2, Wt2, sa0, sa1, sb0, sb1);
        stage_ht(s1 + 1, t0, n0, wave, lane, agg2, Wt2, sa0, sa1, sb0, sb1);
    }
    SBAR; LGKM0; SCHED0; PRIO1;
#pragma unroll
    for (int mi = 0; mi < 4; ++mi)
#pragma unroll
        for (int ni = 0; ni < 2; ++ni)
#pragma unroll
            for (int ks = 0; ks < 2; ++ks)
                acc[mi][ni] = __builtin_amdgcn_mfma_f32_16x16x32_bf16(aF[mi][ks], bF[ni][ks], acc[mi][ni], 0, 0, 0);
    PRIO0; SBAR;

    // ---- P2: read b(ni 2..3); stage B-lo; MFMA Q01 (acc[0..3][2..3]) ----
#pragma unroll
    for (int ni = 0; ni < 2; ++ni)
#pragma unroll
        for (int ks = 0; ks < 2; ++ks) {
            const int row = wn * 64 + (ni + 2) * 16 + laneL;
            bF[ni + 2][ks] = *(const bf16x8*)(pb + row * 64 + (((ks * 4 + laneH) ^ ax) << 3));
        }
    if (STG) stage_ht(s1 + 2, t0, n0, wave, lane, agg2, Wt2, sa0, sa1, sb0, sb1);
    SBAR; LGKM0; SCHED0; PRIO1;
#pragma unroll
    for (int mi = 0; mi < 4; ++mi)
#pragma unroll
        for (int ni = 0; ni < 2; ++ni)
#pragma unroll
            for (int ks = 0; ks < 2; ++ks)
                acc[mi][ni + 2] = __builtin_amdgcn_mfma_f32_16x16x32_bf16(aF[mi][ks], bF[ni + 2][ks], acc[mi][ni + 2], 0, 0, 0);
    PRIO0; SBAR;

    // ---- P3: read a(mi 4..7) into aF; stage B-hi; MFMA Q10 (acc[4..7][0..1]) ----
#pragma unroll
    for (int mi = 0; mi < 4; ++mi)
#pragma unroll
        for (int ks = 0; ks < 2; ++ks) {
            const int row = wm * 128 + (mi + 4) * 16 + laneL;
            aF[mi][ks] = *(const bf16x8*)(pa + row * 64 + (((ks * 4 + laneH) ^ ax) << 3));
        }
    if (STG) stage_ht(s1 + 3, t0, n0, wave, lane, agg2, Wt2, sa0, sa1, sb0, sb1);
    SBAR; LGKM0; SCHED0; PRIO1;
#pragma unroll
    for (int mi = 0; mi < 4; ++mi)
#pragma unroll
        for (int ni = 0; ni < 2; ++ni)
#pragma unroll
            for (int ks = 0; ks < 2; ++ks)
                acc[mi + 4][ni] = __builtin_amdgcn_mfma_f32_16x16x32_bf16(aF[mi][ks], bF[ni][ks], acc[mi + 4][ni], 0, 0, 0);
    PRIO0; SBAR;

    // ---- P4: MFMA Q11 (acc[4..7][2..3]); vmcnt(0); barrier ----
    PRIO1;
#pragma unroll
    for (int mi = 0; mi < 4; ++mi)
#pragma unroll
        for (int ni = 0; ni < 2; ++ni)
#pragma unroll
            for (int ks = 0; ks < 2; ++ks)
                acc[mi + 4][ni + 2] = __builtin_amdgcn_mfma_f32_16x16x32_bf16(aF[mi][ks], bF[ni + 2][ks], acc[mi + 4][ni + 2], 0, 0, 0);
    PRIO0;
    if (VMW) { VMCNT0; }
    SBAR;
}

// ---------------------------------------------------------------------------
// Pass 2: out = relu(agg2[VP2][2048] x Wt2[512][2048]^T), 8-phase-style
// schedule: BM=BN=256, BK=64, 512 thr, 8 waves (2M x 4N), LDS 128 KiB dbuf.
// ---------------------------------------------------------------------------
__global__ void __launch_bounds__(512)
gemm8(const unsigned short* __restrict__ agg2,
      const unsigned short* __restrict__ Wt2,
      float* __restrict__ out) {
    __shared__ unsigned short s_a[2][256 * 64];   // 64 KiB
    __shared__ unsigned short s_b[2][256 * 64];   // 64 KiB

    // bijective XCD chunk swizzle: 392 = 8*49 exactly
    const int orig = blockIdx.x;
    const int wgid = (orig & 7) * (NWG2 / 8) + (orig >> 3);
    const int mt = wgid >> 1, nt = wgid & 1;
    const int t0 = mt * 256, n0 = nt * 256;

    const int tid  = threadIdx.x;
    const int lane = tid & 63;
    const int wave = tid >> 6;                 // 0..7
    const int wm   = wave >> 2;                // M half (128 rows)
    const int wn   = wave & 3;                 // N quarter (64 cols)
    const int laneL = lane & 15, laneH = lane >> 4;

    f32x4 acc[8][4];
#pragma unroll
    for (int mi = 0; mi < 8; ++mi)
#pragma unroll
        for (int ni = 0; ni < 4; ++ni)
            acc[mi][ni] = (f32x4){0.f, 0.f, 0.f, 0.f};

    unsigned short* sa0 = &s_a[0][0]; unsigned short* sa1 = &s_a[1][0];
    unsigned short* sb0 = &s_b[0][0]; unsigned short* sb1 = &s_b[1][0];

    // prologue: stage tile 0 (4 half-tiles), drain, barrier
#pragma unroll
    for (int p = 0; p < 4; ++p)
        stage_ht(p, t0, n0, wave, lane, agg2, Wt2, sa0, sa1, sb0, sb1);
    VMCNT0; SCHED0; SBAR;

    // steady: tiles 0..29 in pairs (bsel folds static), each stages tile+1
    for (int ktp = 0; ktp < 15; ++ktp) {
        group4<true, true>(2 * ktp,     t0, n0, wave, lane, wm, wn, agg2, Wt2, sa0, sa1, sb0, sb1, acc);
        group4<true, true>(2 * ktp + 1, t0, n0, wave, lane, wm, wn, agg2, Wt2, sa0, sa1, sb0, sb1, acc);
    }
    // tile 30 stages tile 31; tile 31 stages nothing, no wait needed after
    group4<true,  true >(30, t0, n0, wave, lane, wm, wn, agg2, Wt2, sa0, sa1, sb0, sb1, acc);
    group4<false, false>(31, t0, n0, wave, lane, wm, wn, agg2, Wt2, sa0, sa1, sb0, sb1, acc);

    // ---- epilogue: ReLU + direct stores (D: col=lane&15, row=(lane>>4)*4+i) ----
#pragma unroll
    for (int mi = 0; mi < 8; ++mi) {
#pragma unroll
        for (int i = 0; i < 4; ++i) {
            int t = t0 + wm * 128 + mi * 16 + laneH * 4 + i;
            if (t < NV) {
#pragma unroll
                for (int ni = 0; ni < 4; ++ni) {
                    int h = n0 + wn * 64 + ni * 16 + laneL;
                    out[(size_t)t * NH + h] = fmaxf(acc[mi][ni][i], 0.f);
                }
            }
        }
    }
}

// ---------------------------------------------------------------------------
// Legacy fallback (R1 pipeline) if workspace is too small.
// ---------------------------------------------------------------------------
__global__ void wt_legacy(const float* __restrict__ W, unsigned short* __restrict__ Wt) {
    int idx = blockIdx.x * 256 + threadIdx.x;
    int l = idx >> 18;
    int r = idx & 262143;
    int k = r >> 9;
    int h = r & 511;
    Wt[(l << 18) + (h << 9) + k] = f2bf(W[idx]);
}
__global__ void __launch_bounds__(256)
legacy_msg(const float* __restrict__ emb, const int* __restrict__ adj,
           const unsigned short* __restrict__ Wt, float* __restrict__ out) {
    __shared__ bf16x8 s_a[32 * 64];
    __shared__ int s_src[32];
    __shared__ int s_tgt[32];
    const int bx = blockIdx.x;
    const int l = bx / (NE / 32);
    const int ebase = (bx % (NE / 32)) * 32;
    const int tid = threadIdx.x, lane = tid & 63, wave = tid >> 6;
    if (tid < 32) {
        int2 p = *(const int2*)(adj + ((size_t)l * NE + ebase + tid) * 2);
        s_src[tid] = p.x; s_tgt[tid] = p.y;
    }
    __syncthreads();
    {
        const int r = tid >> 3, part = tid & 7, k0 = part * 64, rxx = r & 7;
        const float* g = emb + (size_t)s_src[r] * ND + k0;
#pragma unroll
        for (int j = 0; j < 8; ++j) {
            float4 f0 = *(const float4*)(g + j * 8);
            float4 f1 = *(const float4*)(g + j * 8 + 4);
            bf16x8 v;
            v[0]=(short)f2bf(f0.x); v[1]=(short)f2bf(f0.y);
            v[2]=(short)f2bf(f0.z); v[3]=(short)f2bf(f0.w);
            v[4]=(short)f2bf(f1.x); v[5]=(short)f2bf(f1.y);
            v[6]=(short)f2bf(f1.z); v[7]=(short)f2bf(f1.w);
            int slot = (k0 >> 3) + j;
            s_a[r * 64 + (slot ^ rxx)] = v;
        }
    }
    __syncthreads();
    const int c0 = wave * 128, laneL = lane & 15, laneH = lane >> 4, arx = laneL & 7;
    f32x4 acc[2][8];
#pragma unroll
    for (int mf = 0; mf < 2; ++mf)
#pragma unroll
        for (int nf = 0; nf < 8; ++nf) acc[mf][nf] = (f32x4){0.f,0.f,0.f,0.f};
    const bf16x8* wb = (const bf16x8*)(Wt + ((size_t)l << 18));
#pragma unroll
    for (int kc = 0; kc < 16; ++kc) {
        int slot = kc * 4 + laneH;
        bf16x8 a0 = s_a[laneL * 64 + (slot ^ arx)];
        bf16x8 a1 = s_a[(16 + laneL) * 64 + (slot ^ arx)];
#pragma unroll
        for (int nf = 0; nf < 8; ++nf) {
            bf16x8 b = wb[(c0 + nf * 16 + laneL) * 64 + slot];
            acc[0][nf] = __builtin_amdgcn_mfma_f32_16x16x32_bf16(a0, b, acc[0][nf], 0, 0, 0);
            acc[1][nf] = __builtin_amdgcn_mfma_f32_16x16x32_bf16(a1, b, acc[1][nf], 0, 0, 0);
        }
    }
#pragma unroll
    for (int mf = 0; mf < 2; ++mf)
#pragma unroll
        for (int nf = 0; nf < 8; ++nf) {
            int h = c0 + nf * 16 + laneL;
#pragma unroll
            for (int i = 0; i < 4; ++i) {
                int er = mf * 16 + laneH * 4 + i;
                atomicAdd(out + (size_t)s_tgt[er] * NH + h, acc[mf][nf][i]);
            }
        }
}
__global__ void legacy_relu(float* __restrict__ o, int n4) {
    int stride = gridDim.x * blockDim.x;
    for (int i = blockIdx.x * blockDim.x + threadIdx.x; i < n4; i += stride) {
        float4 v = ((float4*)o)[i];
        v.x = fmaxf(v.x, 0.f); v.y = fmaxf(v.y, 0.f);
        v.z = fmaxf(v.z, 0.f); v.w = fmaxf(v.w, 0.f);
        ((float4*)o)[i] = v;
    }
}

extern "C" void kernel_launch(void* const* d_in, const int* in_sizes, int n_in,
                              void* d_out, int out_size, void* d_ws, size_t ws_size,
                              hipStream_t stream) {
    const float* emb = (const float*)d_in[0];   // [V, D] f32
    const int*   adj = (const int*)d_in[1];     // [L, E, 2] i32
    const float* W   = (const float*)d_in[2];   // [L, D, H] f32
    float* out = (float*)d_out;                 // [V, H] f32
    char* ws = (char*)d_ws;

    unsigned short* Wt2  = (unsigned short*)ws;                 // @0,    2 MiB
    int*            cnt  = (int*)(ws + 2621440);                // @2.5M, 802,816 B
    int*            list = (int*)(ws + 3670016);                // @3.5M, 12.25 MiB
    unsigned short* agg2 = (unsigned short*)(ws + (16u << 20)); // @16M,  196 MiB

    const size_t need = (16u << 20) + (size_t)VP2 * KTOT * 2;   // ~212 MiB

    if (ws_size >= need) {
        hipMemsetAsync(cnt, 0, (size_t)VP2 * NL * sizeof(int), stream);
        wt2_kernel<<<(NL * ND * NH) / 256, 256, 0, stream>>>(W, Wt2);
        place_kernel<<<(NL * NE) / 256, 256, 0, stream>>>(adj, cnt, list);
        agg_pull<<<(VP2 * NL) / 4, 256, 0, stream>>>(emb, cnt, list, (unsigned*)agg2);
        gemm8<<<NWG2, 512, 0, stream>>>(agg2, Wt2, out);
    } else {
        // legacy scatter path (R1)
        hipMemsetAsync(d_out, 0, (size_t)out_size * sizeof(float), stream);
        wt_legacy<<<(NL * ND * NH) / 256, 256, 0, stream>>>(W, Wt2);
        legacy_msg<<<NL * (NE / 32), 256, 0, stream>>>(emb, adj, Wt2, out);
        legacy_relu<<<2048, 256, 0, stream>>>(out, out_size / 4);
    }
}

// Round 10
// 260.934 us; speedup vs baseline: 3.5982x; 1.0425x over previous
//
#include <hip/hip_runtime.h>
#include <hip/hip_bf16.h>

// V=50000, D=512, H=512, L=4, E=40000
#define NV 50000
#define VP2 50176          // 196*256, padded target count (M of the big GEMM)
#define ND 512
#define NH 512
#define NL 4
#define NE 40000
#define CAP 16             // per-(target,layer) list capacity; deg ~ Poisson(0.8)
#define KTOT 2048          // NL*ND concatenated K
#define NKT 32             // K-tiles of 64
#define NWG2 392           // (VP2/256) * (512/256) blocks; 392 = 8*49

typedef short bf16x8 __attribute__((ext_vector_type(8)));  // MFMA A/B frag
typedef float f32x4  __attribute__((ext_vector_type(4)));  // MFMA C/D frag

__device__ __forceinline__ unsigned short f2bf(float f) {
    unsigned int u = __float_as_uint(f);
    u += 0x7FFFu + ((u >> 16) & 1u);
    return (unsigned short)(u >> 16);
}
__device__ __forceinline__ unsigned pack_bf2(float x, float y) {
    return (unsigned)f2bf(x) | ((unsigned)f2bf(y) << 16);
}

// async global->LDS, 16B per lane; LDS dest is wave-uniform base + lane*16
#define GLL16(gp, lp) __builtin_amdgcn_global_load_lds( \
    (const __attribute__((address_space(1))) void*)(gp), \
    (__attribute__((address_space(3))) void*)(lp), 16, 0, 0)

// ---------------------------------------------------------------------------
// Wt2[h][l*512+k] = bf16(W[l][k][h])   (2 MiB at ws+0) — B^T, K-concat layout
// ---------------------------------------------------------------------------
__global__ void wt2_kernel(const float* __restrict__ W, unsigned short* __restrict__ Wt2) {
    int idx = blockIdx.x * 256 + threadIdx.x;     // NL*ND*NH = 4194304
    int l = idx >> 18;
    int r = idx & 262143;
    int k = r >> 9;
    int h = r & 511;
    Wt2[((size_t)h << 11) + (l << 9) + k] = f2bf(W[idx]);
}

// ---------------------------------------------------------------------------
// Per-(target,layer) edge lists: cell = tgt*NL + l, entry = src
// ---------------------------------------------------------------------------
__global__ void place_kernel(const int* __restrict__ adj, int* __restrict__ cnt,
                             int* __restrict__ list) {
    int i = blockIdx.x * 256 + threadIdx.x;       // NL*NE = 160000 exact
    int2 p = ((const int2*)adj)[i];               // p.x = src, p.y = tgt
    int l = i / NE;
    int cell = p.y * NL + l;
    int pos = atomicAdd(&cnt[cell], 1);
    if (pos < CAP) list[cell * CAP + pos] = p.x;
}

// ---------------------------------------------------------------------------
// Pass 1: one wave per (t,l). agg2[t][l*512 + d] (bf16 as u32 pairs)
//   = sum over in-edges of emb[src][d], f32 accumulate in regs.
// ---------------------------------------------------------------------------
__global__ void __launch_bounds__(256)
agg_pull(const float* __restrict__ emb, const int* __restrict__ cnt,
         const int* __restrict__ list, unsigned* __restrict__ agg2) {
    const int wid  = blockIdx.x * 4 + (threadIdx.x >> 6);   // over VP2*NL
    const int lane = threadIdx.x & 63;
    const int t    = wid >> 2;
    const int l    = wid & 3;
    const int cell = wid;                                    // t*NL + l
    const size_t dst = (size_t)t * 1024 + l * 256 + lane;    // u32 units

    int n = cnt[cell]; if (n > CAP) n = CAP;
    const int* lst = list + cell * CAP;

    float2 s0 = {0.f,0.f}, s1 = {0.f,0.f}, s2 = {0.f,0.f}, s3 = {0.f,0.f};
    int j = 0;
    for (; j + 2 <= n; j += 2) {
        const float2* p0 = (const float2*)(emb + (size_t)lst[j]     * ND) + lane;
        const float2* p1 = (const float2*)(emb + (size_t)lst[j + 1] * ND) + lane;
        float2 a0 = p0[0], a1 = p0[64], a2 = p0[128], a3 = p0[192];
        float2 b0 = p1[0], b1 = p1[64], b2 = p1[128], b3 = p1[192];
        s0.x += a0.x + b0.x; s0.y += a0.y + b0.y;
        s1.x += a1.x + b1.x; s1.y += a1.y + b1.y;
        s2.x += a2.x + b2.x; s2.y += a2.y + b2.y;
        s3.x += a3.x + b3.x; s3.y += a3.y + b3.y;
    }
    if (j < n) {
        const float2* p0 = (const float2*)(emb + (size_t)lst[j] * ND) + lane;
        float2 a0 = p0[0], a1 = p0[64], a2 = p0[128], a3 = p0[192];
        s0.x += a0.x; s0.y += a0.y;  s1.x += a1.x; s1.y += a1.y;
        s2.x += a2.x; s2.y += a2.y;  s3.x += a3.x; s3.y += a3.y;
    }
    agg2[dst]       = pack_bf2(s0.x, s0.y);
    agg2[dst + 64]  = pack_bf2(s1.x, s1.y);
    agg2[dst + 128] = pack_bf2(s2.x, s2.y);
    agg2[dst + 192] = pack_bf2(s3.x, s3.y);
}

// ---------------------------------------------------------------------------
// Stage one half-tile s (= tile*4 + part; part 0=A-lo,1=A-hi,2=B-lo,3=B-hi).
// Linear LDS dest (wave-uniform base), pre-swizzled global source slot so the
// LDS content at (row, slot) holds global slot (slot ^ (row&7)).
// Verified (R8/R9 pass, bank conflicts = 0).
// ---------------------------------------------------------------------------
__device__ __forceinline__ void stage_ht(
    int s, int t0, int n0, int wave, int lane,
    const unsigned short* __restrict__ agg2, const unsigned short* __restrict__ Wt2,
    unsigned short* sa0, unsigned short* sa1,
    unsigned short* sb0, unsigned short* sb1) {
    const int tile  = s >> 2, part = s & 3;
    const int lr8   = (part & 1) << 7;           // row base within 256-row tile
    const int rowin = lane >> 3;                 // 0..7
    const int slt   = (lane & 7) ^ rowin;        // pre-swizzled 16B slot
    const bool isA  = part < 2;
    const unsigned short* gsrc = isA ? agg2 : Wt2;
    const int gr0 = isA ? t0 : n0;
    unsigned short* ldsbase = isA ? ((tile & 1) ? sa1 : sa0)
                                  : ((tile & 1) ? sb1 : sb0);
#pragma unroll
    for (int c = 0; c < 2; ++c) {
        const int lr = lr8 + (wave * 2 + c) * 8;                     // wave-uniform
        const unsigned short* src = gsrc
            + (size_t)(gr0 + lr + rowin) * KTOT + tile * 64 + slt * 8;
        GLL16(src, ldsbase + lr * 64);
    }
}

// ---------------------------------------------------------------------------
// One K-tile, 2-phase style (T3 minimum recipe, m248v2/m230 verified ~680TF):
//   issue ALL 4 half-tile stages of tile kt+1 (8 GLL16/wave, async)
//   24 ds_read_b128 + 64 MFMA on tile kt (no internal barriers)
//   __syncthreads()  == s_waitcnt vmcnt(0) lgkmcnt(0) + s_barrier
// Stage age at the drain = one full tile (~2000 cyc) >> HBM latency.
// ---------------------------------------------------------------------------
template<bool STG>
__device__ __forceinline__ void tile_step(
    int kt, int t0, int n0, int wave, int lane, int wm, int wn,
    const unsigned short* __restrict__ agg2, const unsigned short* __restrict__ Wt2,
    unsigned short* sa0, unsigned short* sa1,
    unsigned short* sb0, unsigned short* sb1,
    f32x4 (&acc)[8][4]) {
    const int laneL = lane & 15, laneH = lane >> 4;
    const int ax = laneL & 7;
    const unsigned short* pa = (kt & 1) ? sa1 : sa0;
    const unsigned short* pb = (kt & 1) ? sb1 : sb0;

    // ---- issue next-tile stages first (latency hidden under this tile) ----
    if (STG) {
        const int s1 = (kt + 1) * 4;
        stage_ht(s1 + 0, t0, n0, wave, lane, agg2, Wt2, sa0, sa1, sb0, sb1);
        stage_ht(s1 + 1, t0, n0, wave, lane, agg2, Wt2, sa0, sa1, sb0, sb1);
        stage_ht(s1 + 2, t0, n0, wave, lane, agg2, Wt2, sa0, sa1, sb0, sb1);
        stage_ht(s1 + 3, t0, n0, wave, lane, agg2, Wt2, sa0, sa1, sb0, sb1);
    }

    // ---- compute tile kt: b frags + a(mi0-3), MFMA, a(mi4-7), MFMA ----
    bf16x8 aF[4][2], bF[4][2];
#pragma unroll
    for (int ni = 0; ni < 4; ++ni)
#pragma unroll
        for (int ks = 0; ks < 2; ++ks) {
            const int row = wn * 64 + ni * 16 + laneL;
            bF[ni][ks] = *(const bf16x8*)(pb + row * 64 + (((ks * 4 + laneH) ^ ax) << 3));
        }
#pragma unroll
    for (int mi = 0; mi < 4; ++mi)
#pragma unroll
        for (int ks = 0; ks < 2; ++ks) {
            const int row = wm * 128 + mi * 16 + laneL;
            aF[mi][ks] = *(const bf16x8*)(pa + row * 64 + (((ks * 4 + laneH) ^ ax) << 3));
        }
#pragma unroll
    for (int mi = 0; mi < 4; ++mi)
#pragma unroll
        for (int ni = 0; ni < 4; ++ni)
#pragma unroll
            for (int ks = 0; ks < 2; ++ks)
                acc[mi][ni] = __builtin_amdgcn_mfma_f32_16x16x32_bf16(aF[mi][ks], bF[ni][ks], acc[mi][ni], 0, 0, 0);
#pragma unroll
    for (int mi = 0; mi < 4; ++mi)
#pragma unroll
        for (int ks = 0; ks < 2; ++ks) {
            const int row = wm * 128 + (mi + 4) * 16 + laneL;
            aF[mi][ks] = *(const bf16x8*)(pa + row * 64 + (((ks * 4 + laneH) ^ ax) << 3));
        }
#pragma unroll
    for (int mi = 0; mi < 4; ++mi)
#pragma unroll
        for (int ni = 0; ni < 4; ++ni)
#pragma unroll
            for (int ks = 0; ks < 2; ++ks)
                acc[mi + 4][ni] = __builtin_amdgcn_mfma_f32_16x16x32_bf16(aF[mi][ks], bF[ni][ks], acc[mi + 4][ni], 0, 0, 0);

    __syncthreads();   // vmcnt(0): next tile landed; barrier: publish + reuse-safe
}

// ---------------------------------------------------------------------------
// Pass 2: out = relu(agg2[VP2][2048] x Wt2[512][2048]^T), 2-phase schedule:
// BM=BN=256, BK=64, 512 thr, 8 waves (2M x 4N), LDS 128 KiB dbuf,
// ONE barrier per K-tile.
// ---------------------------------------------------------------------------
__global__ void __launch_bounds__(512)
gemm2p(const unsigned short* __restrict__ agg2,
       const unsigned short* __restrict__ Wt2,
       float* __restrict__ out) {
    __shared__ unsigned short s_a[2][256 * 64];   // 64 KiB
    __shared__ unsigned short s_b[2][256 * 64];   // 64 KiB

    // bijective XCD chunk swizzle: 392 = 8*49 exactly
    const int orig = blockIdx.x;
    const int wgid = (orig & 7) * (NWG2 / 8) + (orig >> 3);
    const int mt = wgid >> 1, nt = wgid & 1;
    const int t0 = mt * 256, n0 = nt * 256;

    const int tid  = threadIdx.x;
    const int lane = tid & 63;
    const int wave = tid >> 6;                 // 0..7
    const int wm   = wave >> 2;                // M half (128 rows)
    const int wn   = wave & 3;                 // N quarter (64 cols)
    const int laneL = lane & 15, laneH = lane >> 4;

    f32x4 acc[8][4];
#pragma unroll
    for (int mi = 0; mi < 8; ++mi)
#pragma unroll
        for (int ni = 0; ni < 4; ++ni)
            acc[mi][ni] = (f32x4){0.f, 0.f, 0.f, 0.f};

    unsigned short* sa0 = &s_a[0][0]; unsigned short* sa1 = &s_a[1][0];
    unsigned short* sb0 = &s_b[0][0]; unsigned short* sb1 = &s_b[1][0];

    // prologue: stage tile 0, drain, publish
#pragma unroll
    for (int p = 0; p < 4; ++p)
        stage_ht(p, t0, n0, wave, lane, agg2, Wt2, sa0, sa1, sb0, sb1);
    __syncthreads();

    for (int kt = 0; kt < NKT - 1; ++kt)
        tile_step<true>(kt, t0, n0, wave, lane, wm, wn, agg2, Wt2, sa0, sa1, sb0, sb1, acc);
    tile_step<false>(NKT - 1, t0, n0, wave, lane, wm, wn, agg2, Wt2, sa0, sa1, sb0, sb1, acc);

    // ---- epilogue: ReLU + direct stores (D: col=lane&15, row=(lane>>4)*4+i) ----
#pragma unroll
    for (int mi = 0; mi < 8; ++mi) {
#pragma unroll
        for (int i = 0; i < 4; ++i) {
            int t = t0 + wm * 128 + mi * 16 + laneH * 4 + i;
            if (t < NV) {
#pragma unroll
                for (int ni = 0; ni < 4; ++ni) {
                    int h = n0 + wn * 64 + ni * 16 + laneL;
                    out[(size_t)t * NH + h] = fmaxf(acc[mi][ni][i], 0.f);
                }
            }
        }
    }
}

// ---------------------------------------------------------------------------
// Legacy fallback (R1 pipeline) if workspace is too small.
// ---------------------------------------------------------------------------
__global__ void wt_legacy(const float* __restrict__ W, unsigned short* __restrict__ Wt) {
    int idx = blockIdx.x * 256 + threadIdx.x;
    int l = idx >> 18;
    int r = idx & 262143;
    int k = r >> 9;
    int h = r & 511;
    Wt[(l << 18) + (h << 9) + k] = f2bf(W[idx]);
}
__global__ void __launch_bounds__(256)
legacy_msg(const float* __restrict__ emb, const int* __restrict__ adj,
           const unsigned short* __restrict__ Wt, float* __restrict__ out) {
    __shared__ bf16x8 s_a[32 * 64];
    __shared__ int s_src[32];
    __shared__ int s_tgt[32];
    const int bx = blockIdx.x;
    const int l = bx / (NE / 32);
    const int ebase = (bx % (NE / 32)) * 32;
    const int tid = threadIdx.x, lane = tid & 63, wave = tid >> 6;
    if (tid < 32) {
        int2 p = *(const int2*)(adj + ((size_t)l * NE + ebase + tid) * 2);
        s_src[tid] = p.x; s_tgt[tid] = p.y;
    }
    __syncthreads();
    {
        const int r = tid >> 3, part = tid & 7, k0 = part * 64, rxx = r & 7;
        const float* g = emb + (size_t)s_src[r] * ND + k0;
#pragma unroll
        for (int j = 0; j < 8; ++j) {
            float4 f0 = *(const float4*)(g + j * 8);
            float4 f1 = *(const float4*)(g + j * 8 + 4);
            bf16x8 v;
            v[0]=(short)f2bf(f0.x); v[1]=(short)f2bf(f0.y);
            v[2]=(short)f2bf(f0.z); v[3]=(short)f2bf(f0.w);
            v[4]=(short)f2bf(f1.x); v[5]=(short)f2bf(f1.y);
            v[6]=(short)f2bf(f1.z); v[7]=(short)f2bf(f1.w);
            int slot = (k0 >> 3) + j;
            s_a[r * 64 + (slot ^ rxx)] = v;
        }
    }
    __syncthreads();
    const int c0 = wave * 128, laneL = lane & 15, laneH = lane >> 4, arx = laneL & 7;
    f32x4 acc[2][8];
#pragma unroll
    for (int mf = 0; mf < 2; ++mf)
#pragma unroll
        for (int nf = 0; nf < 8; ++nf) acc[mf][nf] = (f32x4){0.f,0.f,0.f,0.f};
    const bf16x8* wb = (const bf16x8*)(Wt + ((size_t)l << 18));
#pragma unroll
    for (int kc = 0; kc < 16; ++kc) {
        int slot = kc * 4 + laneH;
        bf16x8 a0 = s_a[laneL * 64 + (slot ^ arx)];
        bf16x8 a1 = s_a[(16 + laneL) * 64 + (slot ^ arx)];
#pragma unroll
        for (int nf = 0; nf < 8; ++nf) {
            bf16x8 b = wb[(c0 + nf * 16 + laneL) * 64 + slot];
            acc[0][nf] = __builtin_amdgcn_mfma_f32_16x16x32_bf16(a0, b, acc[0][nf], 0, 0, 0);
            acc[1][nf] = __builtin_amdgcn_mfma_f32_16x16x32_bf16(a1, b, acc[1][nf], 0, 0, 0);
        }
    }
#pragma unroll
    for (int mf = 0; mf < 2; ++mf)
#pragma unroll
        for (int nf = 0; nf < 8; ++nf) {
            int h = c0 + nf * 16 + laneL;
#pragma unroll
            for (int i = 0; i < 4; ++i) {
                int er = mf * 16 + laneH * 4 + i;
                atomicAdd(out + (size_t)s_tgt[er] * NH + h, acc[mf][nf][i]);
            }
        }
}
__global__ void legacy_relu(float* __restrict__ o, int n4) {
    int stride = gridDim.x * blockDim.x;
    for (int i = blockIdx.x * blockDim.x + threadIdx.x; i < n4; i += stride) {
        float4 v = ((float4*)o)[i];
        v.x = fmaxf(v.x, 0.f); v.y = fmaxf(v.y, 0.f);
        v.z = fmaxf(v.z, 0.f); v.w = fmaxf(v.w, 0.f);
        ((float4*)o)[i] = v;
    }
}

extern "C" void kernel_launch(void* const* d_in, const int* in_sizes, int n_in,
                              void* d_out, int out_size, void* d_ws, size_t ws_size,
                              hipStream_t stream) {
    const float* emb = (const float*)d_in[0];   // [V, D] f32
    const int*   adj = (const int*)d_in[1];     // [L, E, 2] i32
    const float* W   = (const float*)d_in[2];   // [L, D, H] f32
    float* out = (float*)d_out;                 // [V, H] f32
    char* ws = (char*)d_ws;

    unsigned short* Wt2  = (unsigned short*)ws;                 // @0,    2 MiB
    int*            cnt  = (int*)(ws + 2621440);                // @2.5M, 802,816 B
    int*            list = (int*)(ws + 3670016);                // @3.5M, 12.25 MiB
    unsigned short* agg2 = (unsigned short*)(ws + (16u << 20)); // @16M,  196 MiB

    const size_t need = (16u << 20) + (size_t)VP2 * KTOT * 2;   // ~212 MiB

    if (ws_size >= need) {
        hipMemsetAsync(cnt, 0, (size_t)VP2 * NL * sizeof(int), stream);
        wt2_kernel<<<(NL * ND * NH) / 256, 256, 0, stream>>>(W, Wt2);
        place_kernel<<<(NL * NE) / 256, 256, 0, stream>>>(adj, cnt, list);
        agg_pull<<<(VP2 * NL) / 4, 256, 0, stream>>>(emb, cnt, list, (unsigned*)agg2);
        gemm2p<<<NWG2, 512, 0, stream>>>(agg2, Wt2, out);
    } else {
        // legacy scatter path (R1)
        hipMemsetAsync(d_out, 0, (size_t)out_size * sizeof(float), stream);
        wt_legacy<<<(NL * ND * NH) / 256, 256, 0, stream>>>(W, Wt2);
        legacy_msg<<<NL * (NE / 32), 256, 0, stream>>>(emb, adj, Wt2, out);
        legacy_relu<<<2048, 256, 0, stream>>>(out, out_size / 4);
    }
}